// Round 9
// baseline (103.885 us; speedup 1.0000x reference)
//
#include <hip/hip_runtime.h>
#include <math.h>

#define NB 8
#define CH 16
#define LL 1024
#define DD 7
#define HH 16

typedef float    v2f  __attribute__((ext_vector_type(2)));
typedef float    v4f  __attribute__((ext_vector_type(4)));
typedef float    v16f __attribute__((ext_vector_type(16)));
typedef short    v8s  __attribute__((ext_vector_type(8)));
typedef unsigned v4u  __attribute__((ext_vector_type(4)));

#if __has_builtin(__builtin_amdgcn_exp2f)
#define EXP2F(x) __builtin_amdgcn_exp2f(x)
#else
#define EXP2F(x) exp2f(x)
#endif

__device__ inline unsigned bf16_rne(float f) {
    unsigned u = __builtin_bit_cast(unsigned, f);
    return (u + 0x7fffu + ((u >> 16) & 1u)) >> 16;
}
__device__ inline unsigned pack_trunc(float a, float b) {
    unsigned ua = __builtin_bit_cast(unsigned, a);
    unsigned ub = __builtin_bit_cast(unsigned, b);
    return (ua >> 16) | (ub & 0xffff0000u);
}

// ---------------------------------------------------------------------------
// Kernel 1: QKV projection via MFMA (bf16 inputs, fp32 accumulate). Unchanged
// from r6 (measured ~2.5 us). Output padded bf16 [mat][n][h][1024][8], Q
// pre-scaled by log2(e)/32, pad slot 7 zeroed.
// grid = 3*NB*16 = 384 blocks, 256 threads.
// ---------------------------------------------------------------------------
__global__ __launch_bounds__(256, 2) void qkv_proj(
    const float* __restrict__ x,
    const float* __restrict__ Wq, const float* __restrict__ bq,
    const float* __restrict__ Wk, const float* __restrict__ bk,
    const float* __restrict__ Wv, const float* __restrict__ bv,
    unsigned short* __restrict__ qkvb)
{
    __shared__ __align__(16) unsigned short Wb[112 * 136];  // 29.8 KB
    __shared__ __align__(16) unsigned short xb[64 * 136];   // 17.0 KB

    int bx  = blockIdx.x;
    int mat = bx / (NB * 16);
    int rem = bx % (NB * 16);
    int n   = rem / 16;
    int l0  = (rem % 16) * 64;

    const float* W = (mat == 0) ? Wq : (mat == 1) ? Wk : Wv;
    const float* b = (mat == 0) ? bq : (mat == 1) ? bk : bv;

    int tid = threadIdx.x;

    {
        const float4* Wsrc = (const float4*)W;
        for (int i4 = tid; i4 < 3136; i4 += 256) {
            int j  = i4 / 28;
            int ii = (i4 - j * 28) * 4;
            float4 w = Wsrc[i4];
            unsigned lo = bf16_rne(w.x) | (bf16_rne(w.y) << 16);
            unsigned hi = bf16_rne(w.z) | (bf16_rne(w.w) << 16);
            *(uint2*)&Wb[j * 136 + ii] = make_uint2(lo, hi);
        }
    }
    for (int idx = tid; idx < 64 * 112; idx += 256) {
        int c  = idx / 448;
        int r  = idx - c * 448;
        int l  = r / 7;
        int dd = r - l * 7;
        xb[l * 136 + c * 7 + dd] =
            (unsigned short)bf16_rne(x[((n * CH + c) * LL + l0 + l) * DD + dd]);
    }
    for (int idx = tid; idx < 64 * 16; idx += 256)
        xb[(idx >> 4) * 136 + 112 + (idx & 15)] = 0;
    for (int idx = tid; idx < 112 * 16; idx += 256)
        Wb[(idx >> 4) * 136 + 112 + (idx & 15)] = 0;

    {
        size_t base = ((size_t)(mat * NB + n) * HH) * (LL * 8);
        for (int idx = tid; idx < 1024; idx += 256) {
            int hh = idx >> 6, l = idx & 63;
            qkvb[base + (size_t)(hh * LL + l0 + l) * 8 + 7] = 0;
        }
    }
    __syncthreads();

    int wv = tid >> 6, lane = tid & 63, l15 = lane & 15, l4 = lane >> 4;

    const unsigned short* Arow = xb + (wv * 16 + l15) * 136 + l4 * 8;
    v8s af[4];
    #pragma unroll
    for (int k4 = 0; k4 < 4; ++k4) af[k4] = *(const v8s*)(Arow + k4 * 32);

    v4f acc[7];
    #pragma unroll
    for (int jt = 0; jt < 7; ++jt) acc[jt] = (v4f){0.f, 0.f, 0.f, 0.f};

    #pragma unroll
    for (int jt = 0; jt < 7; ++jt) {
        const unsigned short* Brow = Wb + (jt * 16 + l15) * 136 + l4 * 8;
        #pragma unroll
        for (int k4 = 0; k4 < 4; ++k4) {
            v8s bf = *(const v8s*)(Brow + k4 * 32);
            acc[jt] = __builtin_amdgcn_mfma_f32_16x16x32_bf16(af[k4], bf, acc[jt], 0, 0, 0);
        }
    }

    const float scale = (mat == 0) ? 0.0450842200277801f /* log2(e)/32 */ : 1.0f;
    size_t mbase = ((size_t)(mat * NB + n) * HH) * (LL * 8);
    #pragma unroll
    for (int jt = 0; jt < 7; ++jt) {
        int j   = jt * 16 + l15;
        int hh  = j / 7;
        int dim = j - hh * 7;
        float bj = b[j];
        int lrow = l0 + wv * 16 + l4 * 4;
        size_t rb = mbase + (size_t)hh * (LL * 8) + (size_t)lrow * 8 + dim;
        #pragma unroll
        for (int r = 0; r < 4; ++r) {
            float val = (acc[jt][r] + bj) * scale;
            qkvb[rb + (size_t)r * 8] = (unsigned short)bf16_rne(val);
        }
    }
}

// ---------------------------------------------------------------------------
// Kernel 2: MFMA flash attention — register P, split-K, SOFTWARE-PIPELINED S.
//  Per wave: 32 q rows x 512 keys (16 chunks of 32). Score tile is double-
//  buffered in registers: S-MFMA for chunk c+1 issues BEFORE the exp burst of
//  chunk c, so MFMA+LDS latency hides under the 128-cycle exp run. Per-wave
//  chunk-start rotation (rot = 2*wave) staggers the exp bursts of the 4
//  resident waves per SIMD across the trans pipe (kills the convoy effect).
//  exp+pack output is directly the PV B-operand; key permutation absorbed in
//  Vt column order; V row 7 == 1.0 gives the denominator (dim-7 of O^T).
//  Key-half partials combine via LDS (plain fp32 adds, no max-rescale).
// grid = NB*HH*8 = 1024 blocks (n,h,qtile 128), 512 thr = 4 q-groups x 2 kh.
// LDS = 36.4 KB; ~100 VGPR -> 4 waves/SIMD, 2 residency rounds.
// ---------------------------------------------------------------------------
__global__ __launch_bounds__(512, 4) void attn(
    const unsigned short* __restrict__ qkvb, float* __restrict__ out)
{
    __shared__ __align__(16) unsigned short Kl[LL * 8];     // 16 KB
    __shared__ __align__(16) unsigned short Vt[8 * 1048];   // 16.4 KB, slot-permuted
    __shared__ __align__(16) float red[128 * 8];            // 4 KB partial exchange

    int bx = blockIdx.x;
    int qt = bx & 7, h = (bx >> 3) & 15, n = bx >> 7;
    int tid  = threadIdx.x;
    int wave = tid >> 6, lane = tid & 63;
    int l31 = lane & 31, g5 = lane >> 5;
    int g  = wave & 3;      // q-group
    int kh = wave >> 2;     // key half

    const unsigned short* Qg = qkvb + (size_t)((0 * NB + n) * HH + h) * (LL * 8);
    const unsigned short* Kg = qkvb + (size_t)((1 * NB + n) * HH + h) * (LL * 8);
    const unsigned short* Vg = qkvb + (size_t)((2 * NB + n) * HH + h) * (LL * 8);

    {   // stage K -> Kl (coalesced 16B, 1024 uint4 by 512 threads)
        const uint4* Ks = (const uint4*)Kg;
        uint4* Kd = (uint4*)Kl;
        Kd[tid]       = Ks[tid];
        Kd[tid + 512] = Ks[tid + 512];
    }
    if (tid < 256) {   // transpose + slot-permute V: global -> regs -> Vt[8][1048]
        const uint4* Vs = (const uint4*)Vg;
        uint4 r0 = Vs[4 * tid], r1 = Vs[4 * tid + 1];
        uint4 r2 = Vs[4 * tid + 2], r3 = Vs[4 * tid + 3];
        const unsigned* p0 = (const unsigned*)&r0;
        const unsigned* p1 = (const unsigned*)&r1;
        const unsigned* p2 = (const unsigned*)&r2;
        const unsigned* p3 = (const unsigned*)&r3;
        int col = ((tid >> 3) << 5) + ((tid & 1) << 3) + (((tid >> 1) & 1) << 2)
                + (((tid >> 2) & 1) << 4);
        #pragma unroll
        for (int d = 0; d < 7; ++d) {
            unsigned a0 = p0[d >> 1], a1 = p1[d >> 1], a2 = p2[d >> 1], a3 = p3[d >> 1];
            unsigned w0, w1;
            if (d & 1) { w0 = (a0 >> 16) | (a1 & 0xffff0000u); w1 = (a2 >> 16) | (a3 & 0xffff0000u); }
            else       { w0 = (a0 & 0xffffu) | (a1 << 16);     w1 = (a2 & 0xffffu) | (a3 << 16); }
            *(uint2*)&Vt[d * 1048 + col] = make_uint2(w0, w1);
        }
        *(uint2*)&Vt[7 * 1048 + col] = make_uint2(0x3f803f80u, 0x3f803f80u);  // ones row
    }
    __syncthreads();

    int q0 = qt * 128 + g * 32 + l31;
    v8s zero8 = {0, 0, 0, 0, 0, 0, 0, 0};
    v8s qf = (lane < 32) ? *(const v8s*)(Qg + (size_t)q0 * 8) : zero8;

    const unsigned short* Vrow = Vt + (l31 & 7) * 1048 + g5 * 8;
    v16f acc = {};

    int kbase = kh * 512;                 // this wave's 512 keys
    int rot   = (wave << 1) & 15;         // de-convoy: per-wave chunk rotation

    // chunk-local key offset (shorts) for rotated chunk index c
    #define KOFF(c) ((kbase + (((c) + rot) & 15) * 32))

    // pipeline prologue: s for rotated chunk 0, prefetch kf for chunk 1
    v8s kf = (lane < 32) ? *(const v8s*)(Kl + KOFF(0) * 8 + l31 * 8) : zero8;
    v16f s_cur = __builtin_amdgcn_mfma_f32_32x32x16_bf16(kf, qf, (v16f){}, 0, 0, 0);
    kf = (lane < 32) ? *(const v8s*)(Kl + KOFF(1) * 8 + l31 * 8) : zero8;

    #pragma unroll 4
    for (int c = 0; c < 16; ++c) {
        // issue next chunk's S-MFMA first: it retires under this chunk's exps
        v16f s_nxt = s_cur;
        if (c < 15)
            s_nxt = __builtin_amdgcn_mfma_f32_32x32x16_bf16(kf, qf, (v16f){}, 0, 0, 0);
        if (c < 14)
            kf = (lane < 32) ? *(const v8s*)(Kl + KOFF(c + 2) * 8 + l31 * 8) : zero8;

        v8s va1 = *(const v8s*)(Vrow + KOFF(c));        // slots 0..15
        v8s va2 = *(const v8s*)(Vrow + KOFF(c) + 16);   // slots 16..31

        unsigned pk[8];
        #pragma unroll
        for (int p = 0; p < 8; ++p)
            pk[p] = pack_trunc(EXP2F(s_cur[2 * p]), EXP2F(s_cur[2 * p + 1]));
        v8s p1 = __builtin_bit_cast(v8s, (v4u){pk[0], pk[1], pk[2], pk[3]});
        v8s p2 = __builtin_bit_cast(v8s, (v4u){pk[4], pk[5], pk[6], pk[7]});

        acc = __builtin_amdgcn_mfma_f32_32x32x16_bf16(va1, p1, acc, 0, 0, 0);
        acc = __builtin_amdgcn_mfma_f32_32x32x16_bf16(va2, p2, acc, 0, 0, 0);

        s_cur = s_nxt;
    }
    #undef KOFF

    // combine key halves: kh=1 writes dims 4*g5..4*g5+3, kh=0 adds + stores
    if (kh == 1) {
        *(float4*)&red[(size_t)(g * 32 + l31) * 8 + 4 * g5] =
            make_float4(acc[0], acc[1], acc[2], acc[3]);
    }
    __syncthreads();
    if (kh == 0) {
        float4 pa = *(const float4*)&red[(size_t)(g * 32 + l31) * 8 + 4 * g5];
        acc[0] += pa.x; acc[1] += pa.y; acc[2] += pa.z; acc[3] += pa.w;

        float rs = __shfl(acc[3], 32 + l31, 64);   // combined denominator (dim 7)
        float* base = out + (size_t)(n * HH + h) * LL * 7 + (size_t)q0 * 7;
        #pragma unroll
        for (int r = 0; r < 4; ++r) {
            int dim = 4 * g5 + r;
            if (dim < 7) base[dim] = acc[r] / rs;
        }
    }
}

extern "C" void kernel_launch(void* const* d_in, const int* in_sizes, int n_in,
                              void* d_out, int out_size, void* d_ws, size_t ws_size,
                              hipStream_t stream) {
    const float* x  = (const float*)d_in[0];
    const float* Wq = (const float*)d_in[1];
    const float* bq = (const float*)d_in[2];
    const float* Wk = (const float*)d_in[3];
    const float* bk = (const float*)d_in[4];
    const float* Wv = (const float*)d_in[5];
    const float* bv = (const float*)d_in[6];
    unsigned short* qkvb = (unsigned short*)d_ws;  // [3][8][16][1024][8] bf16 = 6 MB
    float* o = (float*)d_out;

    qkv_proj<<<dim3(3 * NB * 16), dim3(256), 0, stream>>>(x, Wq, bq, Wk, bk, Wv, bv, qkvb);
    attn<<<dim3(NB * HH * 8), dim3(512), 0, stream>>>(qkvb, o);
}